// Round 1
// baseline (32928.625 us; speedup 1.0000x reference)
//
#include <hip/hip_runtime.h>
#include <math.h>

#define BB 32
#define T_INC 12
#define T_OUTC 12
#define NN 200
#define DIN0 2
#define HH 128
#define DHALF 64
#define NB (NN*BB)
#define DMAX 260
#define NBDMAX ((size_t)NB*DMAX)
#define INV_SQRT_H 0.08838834764831845f

__device__ __forceinline__ float sigmf(float x){ return 1.f/(1.f+expf(-x)); }

// ---------------- GRU step: h' per row (row = n*B + b), 4 rows/block ----------------
__global__ __launch_bounds__(512) void k_gru_step(
    const float* __restrict__ enc_in, const float* __restrict__ Wih,
    const float* __restrict__ Whh, const float* __restrict__ bih,
    const float* __restrict__ bhh, float* __restrict__ h,
    float* __restrict__ outs, int t) {
  int row0 = blockIdx.x * 4;
  int tid = threadIdx.x;
  int rr = tid >> 7;
  int i = tid & 127;
  int row = row0 + rr;
  int n = row / BB, b = row % BB;
  __shared__ float hs[4][HH];
  hs[rr][i] = h[(size_t)row*HH + i];
  __syncthreads();
  float x0 = enc_in[(((size_t)b*T_INC + t)*NN + n)*DIN0 + 0];
  float x1 = enc_in[(((size_t)b*T_INC + t)*NN + n)*DIN0 + 1];
  float ir = Wih[(0*HH+i)*2+0]*x0 + Wih[(0*HH+i)*2+1]*x1 + bih[0*HH+i];
  float iz = Wih[(1*HH+i)*2+0]*x0 + Wih[(1*HH+i)*2+1]*x1 + bih[1*HH+i];
  float ig = Wih[(2*HH+i)*2+0]*x0 + Wih[(2*HH+i)*2+1]*x1 + bih[2*HH+i];
  float hr = bhh[i], hz = bhh[HH+i], hg = bhh[2*HH+i];
  const float* w0 = Whh + (size_t)i*HH;
  const float* w1 = Whh + (size_t)(HH+i)*HH;
  const float* w2 = Whh + (size_t)(2*HH+i)*HH;
  for (int k=0;k<HH;k++) {
    float hv = hs[rr][k];
    hr += w0[k]*hv; hz += w1[k]*hv; hg += w2[k]*hv;
  }
  float r = sigmf(ir+hr);
  float z = sigmf(iz+hz);
  float nn2 = tanhf(ig + r*hg);
  float hn = (1.f-z)*nn2 + z*hs[rr][i];
  h[(size_t)row*HH+i] = hn;
  outs[(((size_t)t*NN+n)*BB+b)*HH + i] = hn;
}

// ---------------- length-attention pooling: block per (n,b), 64 threads ----------------
__global__ void k_att_pool(const float* __restrict__ outs, const float* __restrict__ attW,
                           const float* __restrict__ attb, const float* __restrict__ wlc,
                           float* __restrict__ pooled) {
  int row = blockIdx.x; int n = row / BB, b = row % BB;
  int lane = threadIdx.x; // 64
  __shared__ float o_s[T_INC][HH];
  for (int t=0;t<T_INC;t++)
    for (int k=lane;k<HH;k+=64)
      o_s[t][k] = outs[(((size_t)t*NN+n)*BB+b)*HH + k];
  __syncthreads();
  float wc = wlc[lane];
  float ab = attb[lane];
  float logit[T_INC];
  for (int t=0;t<T_INC;t++) {
    float acc = ab;
    const float* wr = attW + (size_t)lane*HH;
    for (int k=0;k<HH;k++) acc += wr[k]*o_s[t][k];
    logit[t] = fmaxf(acc, 0.f)*wc;
  }
  for (int off=32; off; off>>=1)
    for (int t=0;t<T_INC;t++) logit[t] += __shfl_xor(logit[t], off, 64);
  float mx = -1e30f;
  for (int t=0;t<T_INC;t++) mx = fmaxf(mx, logit[t]);
  float s = 0.f;
  for (int t=0;t<T_INC;t++) { logit[t] = expf(logit[t]-mx); s += logit[t]; }
  float inv = 1.f/s;
  for (int k=lane;k<HH;k+=64) {
    float acc = 0.f;
    for (int t=0;t<T_INC;t++) acc += o_s[t][k]*logit[t];
    pooled[((size_t)b*NN+n)*HH + k] = acc*inv;
  }
}

// ---------------- key/query projections ----------------
__global__ void k_keyquery(const float* __restrict__ pooled, const float* __restrict__ wkey,
                           const float* __restrict__ wqry, float* __restrict__ keym,
                           float* __restrict__ qm) {
  int bn = blockIdx.x; int lane = threadIdx.x; // 64
  __shared__ float p_s[HH];
  p_s[lane] = pooled[(size_t)bn*HH + lane];
  p_s[lane+64] = pooled[(size_t)bn*HH + lane + 64];
  __syncthreads();
  float ka = 0.f, qa = 0.f;
  for (int k=0;k<HH;k++) {
    float pv = p_s[k];
    ka += pv*wkey[(size_t)k*DHALF + lane];
    qa += pv*wqry[(size_t)k*DHALF + lane];
  }
  keym[(size_t)bn*DHALF + lane] = ka;
  qm[(size_t)bn*DHALF + lane] = qa;
}

// ---------------- attention row: scores -> softmax -> topk -> adj row + rowsum ----------------
__global__ void k_attn_row(const float* __restrict__ keym, const float* __restrict__ qm,
                           const int* __restrict__ topkp, float* __restrict__ adj,
                           float* __restrict__ rowsum) {
  int bn = blockIdx.x; int b = bn / NN; int n = bn % NN;
  int tid = threadIdx.x; // 256
  __shared__ float key_s[DHALF];
  __shared__ float attv[256];
  __shared__ float red[256];
  __shared__ int redi[256];
  if (tid < DHALF) key_s[tid] = keym[(size_t)bn*DHALF + tid];
  __syncthreads();
  float sc = -1e30f;
  if (tid < NN) {
    float a = 0.f;
    const float* qrow = qm + ((size_t)b*NN + tid)*DHALF;
    for (int k=0;k<DHALF;k++) a += key_s[k]*qrow[k];
    sc = a * INV_SQRT_H;
  }
  red[tid] = sc; __syncthreads();
  for (int s=128;s>0;s>>=1){ if (tid<s) red[tid]=fmaxf(red[tid],red[tid+s]); __syncthreads(); }
  float mx = red[0]; __syncthreads();
  float e = (tid<NN) ? expf(sc-mx) : 0.f;
  red[tid] = e; __syncthreads();
  for (int s=128;s>0;s>>=1){ if (tid<s) red[tid]+=red[tid+s]; __syncthreads(); }
  float inv = 1.f/red[0]; __syncthreads();
  float av = e*inv;
  attv[tid] = (tid<NN) ? av : -1e30f;
  __syncthreads();
  int Ks = topkp[0]; if (Ks > NN) Ks = NN;
  float kth = -1e30f;
  for (int it=0; it<Ks; it++) {
    red[tid] = attv[tid]; redi[tid] = tid; __syncthreads();
    for (int s=128;s>0;s>>=1){
      if (tid<s && red[tid+s] > red[tid]) { red[tid]=red[tid+s]; redi[tid]=redi[tid+s]; }
      __syncthreads();
    }
    kth = red[0];
    if (tid==0) attv[redi[0]] = -1e30f;
    __syncthreads();
  }
  float aout = 0.f;
  if (tid < NN) {
    aout = (av >= kth) ? av : 0.f;
    if (tid == n) aout += 1.f;
    adj[((size_t)b*NN+n)*NN + tid] = aout;
  }
  red[tid] = aout; __syncthreads();
  for (int s=128;s>0;s>>=1){ if (tid<s) red[tid]+=red[tid+s]; __syncthreads(); }
  if (tid==0) rowsum[bn] = red[0];
}

// ---------------- column sums of adj ----------------
__global__ void k_colsum(const float* __restrict__ adj, float* __restrict__ cs) {
  int b = blockIdx.x;
  for (int j=threadIdx.x; j<NN; j+=blockDim.x) {
    float s = 0.f;
    for (int i=0;i<NN;i++) s += adj[((size_t)b*NN+i)*NN + j];
    cs[(size_t)b*NN + j] = s;
  }
}

// ---------------- build sparse gather lists for s1 and s2 (deterministic, no atomics) --
// s1 gather row i: over adj column i, weight adj[j,i]/rowsum[j]
// s2 gather row i: over adj row i,    weight adj[i,j]/colsum[j]
__global__ void k_sparsify(const float* __restrict__ adj, const float* __restrict__ rs,
                           const float* __restrict__ cs,
                           int* __restrict__ s2cnt, int* __restrict__ s2col, float* __restrict__ s2val,
                           int* __restrict__ s1cnt, int* __restrict__ s1col, float* __restrict__ s1val) {
  int bn = blockIdx.x; int b = bn/NN; int i = bn%NN;
  int lane = threadIdx.x; // 64
  // s2: scan row i
  int cnt = 0;
  for (int j0=0;j0<NN;j0+=64) {
    int j = j0+lane;
    float v = (j<NN) ? adj[((size_t)b*NN+i)*NN + j] : 0.f;
    bool nz = (v != 0.f);
    unsigned long long m = __ballot(nz);
    int pos = cnt + __popcll(m & ((1ull<<lane)-1ull));
    if (nz) { s2col[(size_t)bn*NN+pos] = j; s2val[(size_t)bn*NN+pos] = v / cs[(size_t)b*NN+j]; }
    cnt += __popcll(m);
  }
  if (lane==0) s2cnt[bn] = cnt;
  // s1: scan column i
  cnt = 0;
  for (int j0=0;j0<NN;j0+=64) {
    int j = j0+lane;
    float v = (j<NN) ? adj[((size_t)b*NN+j)*NN + i] : 0.f;
    bool nz = (v != 0.f);
    unsigned long long m = __ballot(nz);
    int pos = cnt + __popcll(m & ((1ull<<lane)-1ull));
    if (nz) { s1col[(size_t)bn*NN+pos] = j; s1val[(size_t)bn*NN+pos] = v / rs[(size_t)b*NN+j]; }
    cnt += __popcll(m);
  }
  if (lane==0) s1cnt[bn] = cnt;
}

// ---------------- concat: xs0[row, :] = [x(strided) , h or r*h] ----------------
__global__ void k_concat(const float* __restrict__ x, int bs, int ns, int din,
                         const float* __restrict__ h, const float* __restrict__ ru,
                         float* __restrict__ xs0, int d) {
  size_t idx = (size_t)blockIdx.x*256 + threadIdx.x;
  if (idx >= (size_t)NB*d) return;
  int row = (int)(idx / d); int c = (int)(idx % d);
  int b = row / NN, n = row % NN;
  float v;
  if (c < din) {
    v = x[(size_t)b*bs + (size_t)n*ns + c];
  } else {
    int k = c - din;
    v = h[(size_t)row*HH + k];
    if (ru) v *= ru[(size_t)row*(2*HH) + k];  // r gate
  }
  xs0[idx] = v;
}

// ---------------- sparse S @ X (optionally Chebyshev combine: Y = 2*S@X - X0) --------
__global__ void k_spmm(const int* __restrict__ cnt, const int* __restrict__ cols,
                       const float* __restrict__ vals, const float* __restrict__ X,
                       const float* __restrict__ X0, float* __restrict__ Y,
                       int d, int cheb) {
  int b = blockIdx.y; int r0 = blockIdx.x * 8;
  int tid = threadIdx.x; // 256
  __shared__ int s_cnt[8];
  __shared__ int s_col[8][NN];
  __shared__ float s_val[8][NN];
  if (tid < 8) s_cnt[tid] = cnt[(size_t)b*NN + r0 + tid];
  __syncthreads();
  for (int r=0;r<8;r++) {
    size_t base = ((size_t)b*NN + r0 + r)*NN;
    int cn = s_cnt[r];
    for (int k2=tid; k2<cn; k2+=256) {
      s_col[r][k2] = cols[base+k2];
      s_val[r][k2] = vals[base+k2];
    }
  }
  __syncthreads();
  for (int r=0;r<8;r++) {
    int row = b*NN + r0 + r;
    int cn = s_cnt[r];
    for (int cc=tid; cc<d; cc+=256) {
      float a = 0.f;
      for (int k2=0;k2<cn;k2++)
        a += s_val[r][k2] * X[((size_t)b*NN + s_col[r][k2])*d + cc];
      if (cheb) a = 2.f*a - X0[(size_t)row*d + cc];
      Y[(size_t)row*d + cc] = a;
    }
  }
}

// ---------------- dense: Y = act( Xm @ W + b ),  Xm[row, dd*5+m] = xs[m][row, dd] -----
#define DD_CHUNK 64
template<int OUT, int ACT>
__global__ void k_dense_act(const float* __restrict__ xs, int d,
                            const float* __restrict__ W, const float* __restrict__ bias,
                            float* __restrict__ Y) {
  const int NCOL = OUT/64;
  int r0 = blockIdx.x * 32;
  int tid = threadIdx.x;
  int g = tid >> 6;
  int c = tid & 63;
  __shared__ float sx[5][32][DD_CHUNK];
  float acc[8][NCOL];
  #pragma unroll
  for (int r=0;r<8;r++)
    #pragma unroll
    for (int q=0;q<NCOL;q++) acc[r][q] = 0.f;
  for (int dd0=0; dd0<d; dd0+=DD_CHUNK) {
    int dlim = min(DD_CHUNK, d-dd0);
    __syncthreads();
    for (int idx = tid; idx < 5*32*dlim; idx += 256) {
      int dd = idx % dlim; int rm = idx / dlim; int r = rm % 32; int m = rm / 32;
      sx[m][r][dd] = xs[(size_t)m*NBDMAX + (size_t)(r0+r)*d + dd0+dd];
    }
    __syncthreads();
    for (int dd=0; dd<dlim; dd++) {
      #pragma unroll
      for (int m=0;m<5;m++) {
        const float* wr = W + ((size_t)(dd0+dd)*5 + m)*OUT + c;
        float w[NCOL];
        #pragma unroll
        for (int q=0;q<NCOL;q++) w[q] = wr[q*64];
        #pragma unroll
        for (int r=0;r<8;r++) {
          float xv = sx[m][g*8+r][dd];
          #pragma unroll
          for (int q=0;q<NCOL;q++) acc[r][q] += xv*w[q];
        }
      }
    }
  }
  #pragma unroll
  for (int r=0;r<8;r++) {
    int row = r0 + g*8 + r;
    #pragma unroll
    for (int q=0;q<NCOL;q++) {
      int o = c + q*64;
      float v = acc[r][q] + bias[o];
      v = (ACT==0) ? sigmf(v) : tanhf(v);
      Y[(size_t)row*OUT + o] = v;
    }
  }
}

// ---------------- h' = u*h + (1-u)*c ----------------
__global__ void k_hnew(const float* __restrict__ ru, const float* __restrict__ h,
                       const float* __restrict__ cb, float* __restrict__ hnew) {
  size_t idx = (size_t)blockIdx.x*256 + threadIdx.x;
  if (idx >= (size_t)NB*HH) return;
  int row = (int)(idx / HH); int k = (int)(idx % HH);
  float u = ru[(size_t)row*(2*HH) + HH + k];
  hnew[idx] = u*h[idx] + (1.f-u)*cb[idx];
}

// ---------------- projection + output + next decoder input ----------------
__global__ void k_proj(const float* __restrict__ h, const float* __restrict__ pW,
                       const float* __restrict__ pb, float* __restrict__ out,
                       float* __restrict__ decx, int t) {
  int row = blockIdx.x; int lane = threadIdx.x; // 64
  const float* hr = h + (size_t)row*HH;
  float v = hr[lane]*pW[lane] + hr[lane+64]*pW[lane+64];
  for (int off=32; off; off>>=1) v += __shfl_xor(v, off, 64);
  if (lane==0) {
    float pv = v + pb[0];
    out[(size_t)t*BB*NN + row] = pv;
    decx[row] = pv;
  }
}

extern "C" void kernel_launch(void* const* d_in, const int* in_sizes, int n_in,
                              void* d_out, int out_size, void* d_ws, size_t ws_size,
                              hipStream_t stream) {
  const float* enc_in = (const float*)d_in[0];
  const float* gWih = (const float*)d_in[2];
  const float* gWhh = (const float*)d_in[3];
  const float* gbih = (const float*)d_in[4];
  const float* gbhh = (const float*)d_in[5];
  const float* attW = (const float*)d_in[6];
  const float* attb = (const float*)d_in[7];
  const float* wlc  = (const float*)d_in[8];
  const float* wkey = (const float*)d_in[9];
  const float* wqry = (const float*)d_in[10];
  // cell params: 0=enc l0, 1=enc l1, 2=dec l0, 3=dec l1
  const float* cWg[4] = {(const float*)d_in[11],(const float*)d_in[15],(const float*)d_in[19],(const float*)d_in[23]};
  const float* cbg[4] = {(const float*)d_in[12],(const float*)d_in[16],(const float*)d_in[20],(const float*)d_in[24]};
  const float* cWc[4] = {(const float*)d_in[13],(const float*)d_in[17],(const float*)d_in[21],(const float*)d_in[25]};
  const float* cbc[4] = {(const float*)d_in[14],(const float*)d_in[18],(const float*)d_in[22],(const float*)d_in[26]};
  const float* pW = (const float*)d_in[27];
  const float* pb = (const float*)d_in[28];
  const int* topkp = (const int*)d_in[29];
  float* out = (float*)d_out;

  float* ws = (float*)d_ws;
  size_t off = 0;
  auto alloc = [&](size_t n) { float* p = ws + off; off += (n + 255) & ~(size_t)255; return p; };
  float* OUTS = alloc((size_t)T_INC*NN*BB*HH);
  float* HGRU = alloc((size_t)NB*HH);
  float* POOL = alloc((size_t)NB*HH);
  float* KEYM = alloc((size_t)NB*DHALF);
  float* QMM  = alloc((size_t)NB*DHALF);
  float* ADJ  = alloc((size_t)BB*NN*NN);
  float* RS   = alloc(NB);
  float* CS   = alloc(NB);
  int*   S2CNT= (int*)alloc(NB);
  int*   S1CNT= (int*)alloc(NB);
  int*   S2COL= (int*)alloc((size_t)NB*NN);
  float* S2VAL= alloc((size_t)NB*NN);
  int*   S1COL= (int*)alloc((size_t)NB*NN);
  float* S1VAL= alloc((size_t)NB*NN);
  float* XS   = alloc(5*NBDMAX);
  float* RU   = alloc((size_t)NB*2*HH);
  float* CB   = alloc((size_t)NB*HH);
  float* H0A  = alloc((size_t)NB*HH);
  float* H0B  = alloc((size_t)NB*HH);
  float* H1A  = alloc((size_t)NB*HH);
  float* H1B  = alloc((size_t)NB*HH);
  float* DECX = alloc(NB);
  if (off*sizeof(float) > ws_size) return;  // workspace too small -> fail loudly in validation

  hipMemsetAsync(HGRU, 0, (size_t)NB*HH*sizeof(float), stream);
  hipMemsetAsync(H0A, 0, (size_t)NB*HH*sizeof(float), stream);
  hipMemsetAsync(H1A, 0, (size_t)NB*HH*sizeof(float), stream);
  hipMemsetAsync(DECX, 0, (size_t)NB*sizeof(float), stream);

  // ---- supports ----
  for (int t=0;t<T_INC;t++)
    k_gru_step<<<NB/4, 512, 0, stream>>>(enc_in, gWih, gWhh, gbih, gbhh, HGRU, OUTS, t);
  k_att_pool<<<NB, 64, 0, stream>>>(OUTS, attW, attb, wlc, POOL);
  k_keyquery<<<NB, 64, 0, stream>>>(POOL, wkey, wqry, KEYM, QMM);
  k_attn_row<<<NB, 256, 0, stream>>>(KEYM, QMM, topkp, ADJ, RS);
  k_colsum<<<BB, 256, 0, stream>>>(ADJ, CS);
  k_sparsify<<<NB, 64, 0, stream>>>(ADJ, RS, CS, S2CNT, S2COL, S2VAL, S1CNT, S1COL, S1VAL);

  float* xs0 = XS;            float* xs1 = XS + NBDMAX;
  float* xs2 = XS + 2*NBDMAX; float* xs3 = XS + 3*NBDMAX;
  float* xs4 = XS + 4*NBDMAX;

  auto cell = [&](const float* x, int bs, int ns, int din,
                  float** hcur, float** halt, int pidx) {
    int d = din + HH;
    size_t nel = (size_t)NB*d;
    dim3 cg((unsigned)((nel + 255)/256));
    dim3 sg(NN/8, BB);
    // gate gconv
    k_concat<<<cg,256,0,stream>>>(x, bs, ns, din, *hcur, nullptr, xs0, d);
    k_spmm<<<sg,256,0,stream>>>(S1CNT,S1COL,S1VAL, xs0, xs0, xs1, d, 0);
    k_spmm<<<sg,256,0,stream>>>(S1CNT,S1COL,S1VAL, xs1, xs0, xs2, d, 1);
    k_spmm<<<sg,256,0,stream>>>(S2CNT,S2COL,S2VAL, xs0, xs0, xs3, d, 0);
    k_spmm<<<sg,256,0,stream>>>(S2CNT,S2COL,S2VAL, xs3, xs0, xs4, d, 1);
    k_dense_act<256,0><<<NB/32,256,0,stream>>>(XS, d, cWg[pidx], cbg[pidx], RU);
    // candidate gconv (input concat uses r*h)
    k_concat<<<cg,256,0,stream>>>(x, bs, ns, din, *hcur, RU, xs0, d);
    k_spmm<<<sg,256,0,stream>>>(S1CNT,S1COL,S1VAL, xs0, xs0, xs1, d, 0);
    k_spmm<<<sg,256,0,stream>>>(S1CNT,S1COL,S1VAL, xs1, xs0, xs2, d, 1);
    k_spmm<<<sg,256,0,stream>>>(S2CNT,S2COL,S2VAL, xs0, xs0, xs3, d, 0);
    k_spmm<<<sg,256,0,stream>>>(S2CNT,S2COL,S2VAL, xs3, xs0, xs4, d, 1);
    k_dense_act<128,1><<<NB/32,256,0,stream>>>(XS, d, cWc[pidx], cbc[pidx], CB);
    k_hnew<<<(NB*HH)/256,256,0,stream>>>(RU, *hcur, CB, *halt);
    float* tswp = *hcur; *hcur = *halt; *halt = tswp;
  };

  float* h0cur = H0A; float* h0alt = H0B;
  float* h1cur = H1A; float* h1alt = H1B;

  // encoder (time-interleaved across layers; equivalent to layer-major scans)
  for (int t=0;t<T_INC;t++) {
    cell(enc_in + (size_t)t*NN*DIN0, T_INC*NN*DIN0, DIN0, DIN0, &h0cur, &h0alt, 0);
    cell(h0cur, NN*HH, HH, HH, &h1cur, &h1alt, 1);
  }
  // decoder (hidden states continue from encoder finals)
  for (int t=0;t<T_OUTC;t++) {
    cell(DECX, NN, 1, 1, &h0cur, &h0alt, 2);
    cell(h0cur, NN*HH, HH, HH, &h1cur, &h1alt, 3);
    k_proj<<<NB,64,0,stream>>>(h1cur, pW, pb, out, DECX, t);
  }
}